// Round 7
// baseline (554.695 us; speedup 1.0000x reference)
//
#include <hip/hip_runtime.h>
#include <stdint.h>
#include <math.h>

#define BB 8
#define SEQ 2048
#define CDIM 384
#define NH 6
#define HD 64
#define QKVN 1152

typedef __attribute__((ext_vector_type(8))) __bf16 bf16x8;
typedef __attribute__((ext_vector_type(4))) float f32x4;
typedef __attribute__((ext_vector_type(4))) unsigned short ushort4v;
typedef __attribute__((ext_vector_type(8))) unsigned short ushort8v;
typedef __attribute__((ext_vector_type(2))) unsigned int uint2v;

__device__ __forceinline__ unsigned short f2bf(float f) {
  unsigned int u = __float_as_uint(f);
  u += 0x7fffu + ((u >> 16) & 1u);
  return (unsigned short)(u >> 16);
}

// fp32 -> bf16 conversion, 4 elems/thread
__global__ void k_convert(const float* __restrict__ src, unsigned short* __restrict__ dst, int n4) {
  int i = blockIdx.x * blockDim.x + threadIdx.x;
  if (i >= n4) return;
  float4 f = reinterpret_cast<const float4*>(src)[i];
  ushort4v u;
  u.x = f2bf(f.x); u.y = f2bf(f.y); u.z = f2bf(f.z); u.w = f2bf(f.w);
  reinterpret_cast<ushort4v*>(dst)[i] = u;
}

__device__ __forceinline__ void gload_lds16(const unsigned short* g, unsigned short* l) {
  __builtin_amdgcn_global_load_lds((const __attribute__((address_space(1))) void*)g,
                                   (__attribute__((address_space(3))) void*)l, 16, 0, 0);
}

// C[M,Nc] = A[M,K] * Bm[Nc,K]^T   (both row-major bf16, K contiguous; m97 structure)
template<int OUT_F32>
__global__ __launch_bounds__(256, 2) void k_gemm_bt(
    const unsigned short* __restrict__ A, const unsigned short* __restrict__ Bm,
    unsigned short* __restrict__ Cb, float* __restrict__ Cf,
    const float* __restrict__ bias, int M, int Nc, int K)
{
  __shared__ unsigned short lA[128 * 32];
  __shared__ unsigned short lB[128 * 32];
  const int t = threadIdx.x;
  const int w = t >> 6, l = t & 63;
  const int wr = w >> 1, wc = w & 1;
  const int row0 = blockIdx.x * 128, col0 = blockIdx.y * 128;
  const f32x4 vzero = {0.f, 0.f, 0.f, 0.f};
  f32x4 acc[4][4];
#pragma unroll
  for (int m = 0; m < 4; ++m)
#pragma unroll
    for (int n = 0; n < 4; ++n) acc[m][n] = vzero;

  const int srow = w * 16 + (l >> 2);
  const int scol = (l & 3) * 8;
  const int lr = l & 15, kc = (l >> 4) * 8;

  for (int k0 = 0; k0 < K; k0 += 32) {
#pragma unroll
    for (int r = 0; r < 2; ++r) {
      gload_lds16(A + (size_t)(row0 + r * 64 + srow) * K + k0 + scol,
                  &lA[(r * 64 + srow) * 32 + scol]);
      gload_lds16(Bm + (size_t)(col0 + r * 64 + srow) * K + k0 + scol,
                  &lB[(r * 64 + srow) * 32 + scol]);
    }
    __syncthreads();
    bf16x8 af[4], bfr[4];
#pragma unroll
    for (int m = 0; m < 4; ++m)
      af[m] = *(const bf16x8*)&lA[(wr * 64 + m * 16 + lr) * 32 + kc];
#pragma unroll
    for (int n = 0; n < 4; ++n)
      bfr[n] = *(const bf16x8*)&lB[(wc * 64 + n * 16 + lr) * 32 + kc];
#pragma unroll
    for (int m = 0; m < 4; ++m)
#pragma unroll
      for (int n = 0; n < 4; ++n)
        acc[m][n] = __builtin_amdgcn_mfma_f32_16x16x32_bf16(af[m], bfr[n], acc[m][n], 0, 0, 0);
    __syncthreads();
  }

#pragma unroll
  for (int m = 0; m < 4; ++m) {
    const int row = row0 + wr * 64 + m * 16 + (l >> 4) * 4;
#pragma unroll
    for (int n = 0; n < 4; ++n) {
      const int col = col0 + wc * 64 + n * 16 + (l & 15);
      if (OUT_F32) {
        const float bv = bias[col];
#pragma unroll
        for (int j = 0; j < 4; ++j)
          Cf[(size_t)(row + j) * Nc + col] = acc[m][n][j] + bv;
      } else {
#pragma unroll
        for (int j = 0; j < 4; ++j)
          Cb[(size_t)(row + j) * Nc + col] = f2bf(acc[m][n][j]);
      }
    }
  }
}

// V slice of qkv (b,n,768 + h*64 + d) -> VT[(b*H+h), d, n]  (bf16)
__global__ void k_vtrans(const unsigned short* __restrict__ qkv, unsigned short* __restrict__ vt)
{
  __shared__ unsigned short tile[64][76];
  const int bh = blockIdx.x;
  const int b = bh / NH, h = bh - b * NH;
  const int n0 = blockIdx.y * 64;
  const int t = threadIdx.x;
  const int rr0 = t >> 4;
  const int c4 = (t & 15) * 4;
  const unsigned short* src = qkv + (size_t)(b * SEQ + n0) * QKVN + 2 * CDIM + h * HD;
#pragma unroll
  for (int rr = 0; rr < 4; ++rr) {
    int n = rr * 16 + rr0;
    ushort4v v = *(const ushort4v*)(src + (size_t)n * QKVN + c4);
    *(ushort4v*)&tile[n][c4] = v;
  }
  __syncthreads();
  unsigned short* dst = vt + (size_t)bh * HD * SEQ + n0;
#pragma unroll
  for (int rr = 0; rr < 4; ++rr) {
    int d = rr * 16 + rr0;
    ushort4v v;
    v.x = tile[c4 + 0][d];
    v.y = tile[c4 + 1][d];
    v.z = tile[c4 + 2][d];
    v.w = tile[c4 + 3][d];
    *(ushort4v*)(dst + (size_t)d * SEQ + c4) = v;
  }
}

// Flash attention v7: r5 structure (swapped QK^T, per-lane softmax) with
// single-buffered K/V + T14 reg-staged split (issue-early / write-late,
// staggered K then V). LDS 24KB -> 6 blocks/CU; grid 1536 fully resident.
__global__ __launch_bounds__(256, 6) void k_attn(
    const unsigned short* __restrict__ qkv, const float* __restrict__ mask,
    const unsigned short* __restrict__ vt, unsigned short* __restrict__ aout)
{
  const int bid = blockIdx.x;
  const int b = bid & 7;            // batch -> XCD
  const int g2 = bid >> 3;          // 0..191
  const int h = g2 % NH;            // heads of same (b,nt) co-dispatched (mask L2 reuse)
  const int nt = g2 / NH;           // 0..31
  const int t = threadIdx.x;
  const int w = t >> 6, l = t & 63;
  const int gk = l >> 4, c = l & 15;
  const int q0 = nt * 64 + w * 16;  // wave handles q0..q0+15

  __shared__ unsigned short lK[4096];   // 64 keys x 64 d, granule-XOR-swizzled
  __shared__ unsigned short lV[4096];   // 64 d x 64 n (from VT)
  __shared__ unsigned int lP[4][512];   // per-wave 16q x 32 u32, XOR-swizzled
  unsigned int* prow = lP[w] + c * 32;

  const unsigned short* qb = qkv + (size_t)(b * SEQ + q0) * QKVN + h * HD;
  const unsigned short* kb = qkv + (size_t)(b * SEQ) * QKVN + CDIM + h * HD;
  const unsigned short* vb = vt + (size_t)(b * NH + h) * HD * SEQ;
  const float* mrowc = mask + ((size_t)b * SEQ + q0 + c) * SEQ + 4 * gk;

  // staging: thread t covers row trow, granule tg; global linear, LDS write
  // swizzled (phys granule = tg ^ (trow&7)); read side uses matching XOR.
  const int trow = t >> 3, tg = t & 7;
  const size_t kSrc = (size_t)trow * QKVN + tg * 8;
  const size_t vSrc = (size_t)trow * SEQ + tg * 8;
  const int ldst = trow * 64 + (tg ^ (trow & 7)) * 8;

  // fragment ds_read offsets (elems)
  const int fr0 = c * 64 + ((gk) ^ (c & 7)) * 8;
  const int fr1 = c * 64 + ((4 + gk) ^ (c & 7)) * 8;
  const int cx = (c & 7) << 2;        // P-slot XOR swizzle

  // Q as B'-frag (col=q=c, d-chunk gk*8), pre-scaled by rsqrt(D)*log2(e)
  bf16x8 qf0 = *(const bf16x8*)(qb + (size_t)c * QKVN + gk * 8);
  bf16x8 qf1 = *(const bf16x8*)(qb + (size_t)c * QKVN + 32 + gk * 8);
#pragma unroll
  for (int i = 0; i < 8; ++i) {
    qf0[i] = (__bf16)((float)qf0[i] * 0.18033688f);
    qf1[i] = (__bf16)((float)qf1[i] * 0.18033688f);
  }

  const f32x4 vzero = {0.f, 0.f, 0.f, 0.f};
  f32x4 acco[4];
  float mreg = -INFINITY, asum = 0.f;
#pragma unroll
  for (int dt = 0; dt < 4; ++dt) acco[dt] = vzero;

  // prologue: stage tile 0 via regs, first mask tile
  {
    ushort8v k0 = *(const ushort8v*)(kb + kSrc);
    ushort8v k1 = *(const ushort8v*)(kb + (size_t)32 * QKVN + kSrc);
    ushort8v v0 = *(const ushort8v*)(vb + vSrc);
    ushort8v v1 = *(const ushort8v*)(vb + (size_t)32 * SEQ + vSrc);
    *(ushort8v*)&lK[ldst] = k0;
    *(ushort8v*)&lK[2048 + ldst] = k1;
    *(ushort8v*)&lV[ldst] = v0;
    *(ushort8v*)&lV[2048 + ldst] = v1;
  }
  float4 mk[4];
#pragma unroll
  for (int j = 0; j < 4; ++j)
    mk[j] = *(const float4*)(mrowc + 16 * j);
  __syncthreads();

  for (int kt = 0; kt < SEQ; kt += 64) {
    const bool haveNext = (kt + 64 < SEQ);

    // issue next-K loads early (T14: latency hides under QK^T)
    ushort8v kr0, kr1;
    if (haveNext) {
      kr0 = *(const ushort8v*)(kb + (size_t)(kt + 64) * QKVN + kSrc);
      kr1 = *(const ushort8v*)(kb + (size_t)(kt + 96) * QKVN + kSrc);
    }

    // swapped QK^T: S^T[key=16j+4gk+r][q=c]
    f32x4 s[4];
#pragma unroll
    for (int j = 0; j < 4; ++j) {
      bf16x8 kfa = *(const bf16x8*)&lK[j * 1024 + fr0];
      bf16x8 kfb = *(const bf16x8*)&lK[j * 1024 + fr1];
      s[j] = __builtin_amdgcn_mfma_f32_16x16x32_bf16(kfa, qf0, vzero, 0, 0, 0);
      s[j] = __builtin_amdgcn_mfma_f32_16x16x32_bf16(kfb, qf1, s[j], 0, 0, 0);
    }

    __syncthreads();               // all waves done reading lK
    if (haveNext) {                // write next K (hides under softmax)
      *(ushort8v*)&lK[ldst] = kr0;
      *(ushort8v*)&lK[2048 + ldst] = kr1;
    }

    // issue next-V loads (latency hides under softmax + P + PV)
    ushort8v vr0, vr1;
    if (haveNext) {
      vr0 = *(const ushort8v*)(vb + (kt + 64) + vSrc);
      vr1 = *(const ushort8v*)(vb + (kt + 64) + (size_t)32 * SEQ + vSrc);
    }

    // masked log2-scores in place
#pragma unroll
    for (int j = 0; j < 4; ++j) {
      const float* mkf = (const float*)&mk[j];
#pragma unroll
      for (int r = 0; r < 4; ++r)
        s[j][r] = fmaf(mkf[r], -144269.50f, s[j][r]);
    }

    // reload mask for next tile (consumed next iter)
    if (haveNext) {
#pragma unroll
      for (int j = 0; j < 4; ++j)
        mk[j] = *(const float4*)(mrowc + kt + 64 + 16 * j);
    }

    // per-lane max over own 16 keys, then cross-group
    float tm = fmaxf(fmaxf(fmaxf(s[0][0], s[0][1]), fmaxf(s[0][2], s[0][3])),
                     fmaxf(fmaxf(s[1][0], s[1][1]), fmaxf(s[1][2], s[1][3])));
    tm = fmaxf(tm, fmaxf(fmaxf(fmaxf(s[2][0], s[2][1]), fmaxf(s[2][2], s[2][3])),
                         fmaxf(fmaxf(s[3][0], s[3][1]), fmaxf(s[3][2], s[3][3]))));
    tm = fmaxf(tm, __shfl_xor(tm, 16));
    tm = fmaxf(tm, __shfl_xor(tm, 32));

    // defer-rescale (T13, thr=8 in log2 domain)
    if (__any(tm > mreg + 8.f)) {
      const float mn = fmaxf(mreg, tm);
      const float al = __builtin_amdgcn_exp2f(mreg - mn);
      mreg = mn;
      asum *= al;
      float alr[4];
#pragma unroll
      for (int r = 0; r < 4; ++r)
        alr[r] = __shfl(al, 20 * gk + r);
#pragma unroll
      for (int dt = 0; dt < 4; ++dt)
#pragma unroll
        for (int r = 0; r < 4; ++r)
          acco[dt][r] *= alr[r];
    }

    // P = exp2(s - m) in place; row-sum
#pragma unroll
    for (int j = 0; j < 4; ++j)
#pragma unroll
      for (int r = 0; r < 4; ++r)
        s[j][r] = __builtin_amdgcn_exp2f(s[j][r] - mreg);
    float rs = ((s[0][0] + s[0][1]) + (s[0][2] + s[0][3]))
             + ((s[1][0] + s[1][1]) + (s[1][2] + s[1][3]))
             + ((s[2][0] + s[2][1]) + (s[2][2] + s[2][3]))
             + ((s[3][0] + s[3][1]) + (s[3][2] + s[3][3]));
    rs += __shfl_xor(rs, 16);
    rs += __shfl_xor(rs, 32);
    asum += rs;

    // pack P to bf16x2, redistribute keys via swizzled LDS (b64 writes)
    __asm__ volatile("" ::: "memory");
#pragma unroll
    for (int j = 0; j < 4; ++j) {
      uint2v pr;
      asm("v_cvt_pk_bf16_f32 %0, %1, %2" : "=v"(pr.x) : "v"(s[j][0]), "v"(s[j][1]));
      asm("v_cvt_pk_bf16_f32 %0, %1, %2" : "=v"(pr.y) : "v"(s[j][2]), "v"(s[j][3]));
      *(uint2v*)(prow + ((8 * j + 2 * gk) ^ cx)) = pr;
    }
    __asm__ volatile("" ::: "memory");
    bf16x8 pf0 = *(const bf16x8*)(prow + ((4 * gk) ^ cx));
    bf16x8 pf1 = *(const bf16x8*)(prow + ((16 + 4 * gk) ^ cx));
    __asm__ volatile("" ::: "memory");

    // PV: O[q=4gk+r][d=dt*16+c]
#pragma unroll
    for (int dt = 0; dt < 4; ++dt) {
      bf16x8 vf0 = *(const bf16x8*)&lV[dt * 1024 + fr0];
      bf16x8 vf1 = *(const bf16x8*)&lV[dt * 1024 + fr1];
      acco[dt] = __builtin_amdgcn_mfma_f32_16x16x32_bf16(pf0, vf0, acco[dt], 0, 0, 0);
      acco[dt] = __builtin_amdgcn_mfma_f32_16x16x32_bf16(pf1, vf1, acco[dt], 0, 0, 0);
    }

    __syncthreads();               // all waves done reading lV
    if (haveNext) {                // write next V (visible by next barrier1)
      *(ushort8v*)&lV[ldst] = vr0;
      *(ushort8v*)&lV[2048 + ldst] = vr1;
    }
  }

  // normalize: asum lives at holder lane c'=4gk+r; out rows q0+4gk+r
  float invr[4];
#pragma unroll
  for (int r = 0; r < 4; ++r)
    invr[r] = 1.0f / __shfl(asum, 20 * gk + r);
  unsigned short* ob = aout + (size_t)(b * SEQ + q0) * CDIM + h * HD;
#pragma unroll
  for (int r = 0; r < 4; ++r)
#pragma unroll
    for (int dt = 0; dt < 4; ++dt)
      ob[(size_t)(4 * gk + r) * CDIM + dt * 16 + c] = f2bf(acco[dt][r] * invr[r]);
}

extern "C" void kernel_launch(void* const* d_in, const int* in_sizes, int n_in,
                              void* d_out, int out_size, void* d_ws, size_t ws_size,
                              hipStream_t stream) {
  (void)in_sizes; (void)n_in; (void)out_size; (void)ws_size;
  const float* x      = (const float*)d_in[0];
  const float* mask   = (const float*)d_in[2];
  const float* qkv_w  = (const float*)d_in[3];
  const float* proj_w = (const float*)d_in[4];
  const float* proj_b = (const float*)d_in[5];
  float* out = (float*)d_out;
  char* ws = (char*)d_ws;

  unsigned short* xb    = (unsigned short*)(ws + 0);         // x bf16:      12,582,912
  unsigned short* wqb   = (unsigned short*)(ws + 12582912);  // qkv_w bf16:     884,736
  unsigned short* wpb   = (unsigned short*)(ws + 13467648);  // proj_w bf16:    294,912
  unsigned short* qkvb  = (unsigned short*)(ws + 13762560);  // qkv bf16:    37,748,736
  unsigned short* vtb   = (unsigned short*)(ws + 51511296);  // V^T bf16:    12,582,912
  unsigned short* aoutb = (unsigned short*)(ws + 64094208);  // attn out:    12,582,912

  k_convert<<<6144, 256, 0, stream>>>(x, xb, 1572864);
  k_convert<<<432, 256, 0, stream>>>(qkv_w, wqb, 110592);
  k_convert<<<144, 256, 0, stream>>>(proj_w, wpb, 36864);
  k_gemm_bt<0><<<dim3(128, 9), 256, 0, stream>>>(xb, wqb, qkvb, nullptr, nullptr, 16384, 1152, 384);
  k_vtrans<<<dim3(48, 32), 256, 0, stream>>>(qkvb, vtb);
  k_attn<<<1536, 256, 0, stream>>>(qkvb, mask, vtb, aoutb);
  k_gemm_bt<1><<<dim3(128, 3), 256, 0, stream>>>(aoutb, wpb, nullptr, out, proj_b, 16384, 384, 384);
}